// Round 10
// baseline (271.475 us; speedup 1.0000x reference)
//
#include <hip/hip_runtime.h>

// B=8, N=1024, C=1024, H=16, HD=64
// R10: GEMMs = 256x128 tile, 512 threads (8 waves, 4m x 2n of 64x64),
//      3-stage LDS (72KB), distance-2, vmcnt(3) raw barriers.
//      -> 16 waves/CU resident (vs 8), B-traffic halved.
//      Attention (R9 dbuf register-P) and convert unchanged.

typedef __attribute__((ext_vector_type(8))) short bf16x8;
typedef __attribute__((ext_vector_type(4))) short bf16x4;
typedef __attribute__((ext_vector_type(4))) float f32x4;

__device__ __forceinline__ short f2bf(float f) {
    union { float f; unsigned u; } x;
    x.f = f;
    unsigned r = x.u + 0x7fffu + ((x.u >> 16) & 1u);  // RNE
    return (short)(r >> 16);
}

__device__ __forceinline__ void load_lds16(const void* g, void* l) {
    __builtin_amdgcn_global_load_lds((const __attribute__((address_space(1))) unsigned*)g,
                                     (__attribute__((address_space(3))) unsigned*)l,
                                     16, 0, 0);
}

// ---------------- merged fp32 -> bf16 convert ----------------
__global__ __launch_bounds__(256) void convert_all(const float* __restrict__ x,
                                                   const float* __restrict__ wqkv,
                                                   const float* __restrict__ wproj,
                                                   short* __restrict__ xb,
                                                   short* __restrict__ wqkvb,
                                                   short* __restrict__ wprojb) {
    int i = blockIdx.x * 256 + threadIdx.x;
    const float* src;
    short* dst;
    int j;
    if (i < 2097152)      { src = x;     dst = xb;     j = i; }
    else if (i < 2883584) { src = wqkv;  dst = wqkvb;  j = i - 2097152; }
    else                  { src = wproj; dst = wprojb; j = i - 2883584; }
    float4 v = *(const float4*)(src + j * 4);
    unsigned lo = (unsigned short)f2bf(v.x) | ((unsigned)(unsigned short)f2bf(v.y) << 16);
    unsigned hi = (unsigned short)f2bf(v.z) | ((unsigned)(unsigned short)f2bf(v.w) << 16);
    uint2 p; p.x = lo; p.y = hi;
    *(uint2*)(dst + j * 4) = p;
}

// ---------------- QKV GEMM: 256x128 tile, 8 waves, 3-stage vmcnt(3) ----------------
// M=8192, N=3072, K=1024. grid (24, 32): x-major -> 24 consecutive blocks share A-panel.
__global__ __launch_bounds__(512) void gemm_qkv(const short* __restrict__ A,
                                                const short* __restrict__ Bt,
                                                short* __restrict__ q,
                                                short* __restrict__ k,
                                                short* __restrict__ vt) {
    __shared__ alignas(16) short As[3][256][32];   // 48 KB
    __shared__ alignas(16) short Bs[3][128][32];   // 24 KB
    const int K = 1024;
    const int m0 = blockIdx.y * 256;
    const int n0 = blockIdx.x * 128;
    const int t = threadIdx.x;
    const int w = t >> 6, lane = t & 63, quad = lane >> 4, l16 = lane & 15;
    const int wm = (w >> 1) * 64, wn = (w & 1) * 64;   // 4m x 2n of 64x64
    const int srow = lane >> 2;        // 0..15
    const int sc8 = (lane & 3) * 8;

    const short* Abase = &A[(m0 + w * 32 + srow) * K + sc8];   // wave stages A rows [w*32, w*32+32)
    const short* Bbase = &Bt[(n0 + w * 16 + srow) * K + sc8];  // wave stages B rows [w*16, w*16+16)

    f32x4 acc[4][4];
    for (int mi = 0; mi < 4; ++mi)
        for (int ni = 0; ni < 4; ++ni)
            acc[mi][ni] = (f32x4){0.f, 0.f, 0.f, 0.f};

    // prologue: stage tiles 0 and 1 (3 loads each per wave)
    #pragma unroll
    for (int p = 0; p < 2; ++p) {
        load_lds16(Abase + p * 32,          &As[p][w * 32][0]);
        load_lds16(Abase + 16 * K + p * 32, &As[p][w * 32 + 16][0]);
        load_lds16(Bbase + p * 32,          &Bs[p][w * 16][0]);
    }

    #pragma unroll
    for (int it = 0; it < 32; ++it) {
        // own-tile loads drained, next-tile loads stay in flight
        if (it == 31) asm volatile("s_waitcnt vmcnt(0) lgkmcnt(0)" ::: "memory");
        else          asm volatile("s_waitcnt vmcnt(3) lgkmcnt(0)" ::: "memory");
        asm volatile("s_barrier" ::: "memory");
        if (it < 30) {
            const int b2 = (it + 2) % 3;
            load_lds16(Abase + (it + 2) * 32,          &As[b2][w * 32][0]);
            load_lds16(Abase + 16 * K + (it + 2) * 32, &As[b2][w * 32 + 16][0]);
            load_lds16(Bbase + (it + 2) * 32,          &Bs[b2][w * 16][0]);
        }
        const int cb = it % 3;
        bf16x8 af[4], bfr[4];
        for (int i = 0; i < 4; ++i) af[i]  = *(const bf16x8*)&As[cb][wm + i * 16 + l16][quad * 8];
        for (int i = 0; i < 4; ++i) bfr[i] = *(const bf16x8*)&Bs[cb][wn + i * 16 + l16][quad * 8];
        for (int mi = 0; mi < 4; ++mi)
            for (int ni = 0; ni < 4; ++ni)
                acc[mi][ni] = __builtin_amdgcn_mfma_f32_16x16x32_bf16(af[mi], bfr[ni], acc[mi][ni], 0, 0, 0);
    }

    const float QS = 0.125f * 1.44269504088896f;
    for (int ni = 0; ni < 4; ++ni) {
        int col = n0 + wn + ni * 16 + l16;
        int sect = col >> 10;
        int c = col & 1023;
        int h = c >> 6, d = c & 63;
        for (int mi = 0; mi < 4; ++mi) {
            for (int r = 0; r < 4; ++r) {
                int m = m0 + wm + mi * 16 + quad * 4 + r;
                int b = m >> 10, i = m & 1023;
                float v = acc[mi][ni][r];
                if (sect == 0)      q[((b * 16 + h) * 1024 + i) * 64 + d] = f2bf(v * QS);
                else if (sect == 1) k[((b * 16 + h) * 1024 + i) * 64 + d] = f2bf(v);
                else                vt[((b * 16 + h) * 64 + d) * 1024 + i] = f2bf(v);
            }
        }
    }
}

// ---------------- Flash attention: dbuf K/V, 1 barrier/jt, register P (R9) ----------------
__global__ __launch_bounds__(256) void attn_kernel(const short* __restrict__ q,
                                                   const short* __restrict__ k,
                                                   const short* __restrict__ vt,
                                                   short* __restrict__ ao) {
    __shared__ alignas(16) short Ks[2][64][72];
    __shared__ alignas(16) short Vs[2][64][72];

    const int bh = blockIdx.y, qt = blockIdx.x;
    const int t = threadIdx.x, w = t >> 6, lane = t & 63, quad = lane >> 4, l16 = lane & 15;
    const short* qg = q  + (bh * 1024 + qt * 128) * 64;
    const short* kg = k  + bh * 65536;
    const short* vg = vt + bh * 65536;

    bf16x8 qf[2][2];
    for (int mi = 0; mi < 2; ++mi) {
        const short* qr = qg + (w * 32 + mi * 16 + l16) * 64;
        qf[mi][0] = *(const bf16x8*)(qr + quad * 8);
        qf[mi][1] = *(const bf16x8*)(qr + 32 + quad * 8);
    }

    const int r0 = t >> 3,          c80 = (t & 7) * 8;
    const int r1 = (t + 256) >> 3,  c81 = c80;

    float rs[2] = {0.f, 0.f};
    f32x4 oaccT[2][4];
    for (int mi = 0; mi < 2; ++mi)
        for (int dt = 0; dt < 4; ++dt) oaccT[mi][dt] = (f32x4){0.f, 0.f, 0.f, 0.f};

    {
        float4 a = *(const float4*)&kg[r0 * 64 + c80];
        float4 b = *(const float4*)&kg[r1 * 64 + c81];
        float4 c = *(const float4*)&vg[r0 * 1024 + c80];
        float4 d = *(const float4*)&vg[r1 * 1024 + c81];
        *(float4*)&Ks[0][r0][c80] = a;  *(float4*)&Ks[0][r1][c81] = b;
        *(float4*)&Vs[0][r0][c80] = c;  *(float4*)&Vs[0][r1][c81] = d;
    }

    for (int jt = 0; jt < 16; ++jt) {
        const int cur = jt & 1;
        asm volatile("s_waitcnt lgkmcnt(0)" ::: "memory");
        asm volatile("s_barrier" ::: "memory");

        float4 kr0, kr1, vr0, vr1;
        if (jt < 15) {
            int jn = jt + 1;
            kr0 = *(const float4*)&kg[(jn * 64 + r0) * 64 + c80];
            kr1 = *(const float4*)&kg[(jn * 64 + r1) * 64 + c81];
            vr0 = *(const float4*)&vg[r0 * 1024 + jn * 64 + c80];
            vr1 = *(const float4*)&vg[r1 * 1024 + jn * 64 + c81];
        }

        for (int js = 0; js < 4; ++js) {
            bf16x8 kf0 = *(const bf16x8*)&Ks[cur][js * 16 + l16][quad * 8];
            bf16x8 kf1 = *(const bf16x8*)&Ks[cur][js * 16 + l16][32 + quad * 8];
            bf16x4 vtf[4];
            for (int dt = 0; dt < 4; ++dt)
                vtf[dt] = *(const bf16x4*)&Vs[cur][dt * 16 + l16][js * 16 + quad * 4];
            for (int mi = 0; mi < 2; ++mi) {
                f32x4 s = (f32x4){0.f, 0.f, 0.f, 0.f};
                s = __builtin_amdgcn_mfma_f32_16x16x32_bf16(kf0, qf[mi][0], s, 0, 0, 0);
                s = __builtin_amdgcn_mfma_f32_16x16x32_bf16(kf1, qf[mi][1], s, 0, 0, 0);
                bf16x4 pfrag;
                for (int r = 0; r < 4; ++r) {
                    float p = __builtin_amdgcn_exp2f(s[r]);
                    rs[mi] += p;
                    pfrag[r] = f2bf(p);
                }
                for (int dt = 0; dt < 4; ++dt)
                    oaccT[mi][dt] = __builtin_amdgcn_mfma_f32_16x16x16bf16_1k(
                        vtf[dt], pfrag, oaccT[mi][dt], 0, 0, 0);
            }
        }

        if (jt < 15) {
            const int nxt = cur ^ 1;
            *(float4*)&Ks[nxt][r0][c80] = kr0;  *(float4*)&Ks[nxt][r1][c81] = kr1;
            *(float4*)&Vs[nxt][r0][c80] = vr0;  *(float4*)&Vs[nxt][r1][c81] = vr1;
        }
    }

    for (int mi = 0; mi < 2; ++mi) {
        rs[mi] += __shfl_xor(rs[mi], 16, 64);
        rs[mi] += __shfl_xor(rs[mi], 32, 64);
    }

    const int b = bh >> 4, h = bh & 15;
    for (int mi = 0; mi < 2; ++mi) {
        float inv = 1.0f / rs[mi];
        int i = qt * 128 + w * 32 + mi * 16 + l16;
        short* aor = ao + (b * 1024 + i) * 1024 + h * 64;
        for (int dt = 0; dt < 4; ++dt) {
            bf16x4 o4;
            for (int r = 0; r < 4; ++r) o4[r] = f2bf(oaccT[mi][dt][r] * inv);
            *(bf16x4*)(aor + dt * 16 + quad * 4) = o4;
        }
    }
}

// ---------------- Out-proj GEMM: 256x128 tile, 8 waves, 3-stage vmcnt(3) ----------------
// M=8192, N=1024. grid (8, 32) = 256 blocks = 1 per CU.
__global__ __launch_bounds__(512) void gemm_proj(const short* __restrict__ A,
                                                 const short* __restrict__ Bt,
                                                 const float* __restrict__ bias,
                                                 float* __restrict__ out) {
    __shared__ alignas(16) short As[3][256][32];
    __shared__ alignas(16) short Bs[3][128][32];
    const int K = 1024;
    const int m0 = blockIdx.y * 256;
    const int n0 = blockIdx.x * 128;
    const int t = threadIdx.x;
    const int w = t >> 6, lane = t & 63, quad = lane >> 4, l16 = lane & 15;
    const int wm = (w >> 1) * 64, wn = (w & 1) * 64;
    const int srow = lane >> 2;
    const int sc8 = (lane & 3) * 8;

    const short* Abase = &A[(m0 + w * 32 + srow) * K + sc8];
    const short* Bbase = &Bt[(n0 + w * 16 + srow) * K + sc8];

    f32x4 acc[4][4];
    for (int mi = 0; mi < 4; ++mi)
        for (int ni = 0; ni < 4; ++ni)
            acc[mi][ni] = (f32x4){0.f, 0.f, 0.f, 0.f};

    #pragma unroll
    for (int p = 0; p < 2; ++p) {
        load_lds16(Abase + p * 32,          &As[p][w * 32][0]);
        load_lds16(Abase + 16 * K + p * 32, &As[p][w * 32 + 16][0]);
        load_lds16(Bbase + p * 32,          &Bs[p][w * 16][0]);
    }

    #pragma unroll
    for (int it = 0; it < 32; ++it) {
        if (it == 31) asm volatile("s_waitcnt vmcnt(0) lgkmcnt(0)" ::: "memory");
        else          asm volatile("s_waitcnt vmcnt(3) lgkmcnt(0)" ::: "memory");
        asm volatile("s_barrier" ::: "memory");
        if (it < 30) {
            const int b2 = (it + 2) % 3;
            load_lds16(Abase + (it + 2) * 32,          &As[b2][w * 32][0]);
            load_lds16(Abase + 16 * K + (it + 2) * 32, &As[b2][w * 32 + 16][0]);
            load_lds16(Bbase + (it + 2) * 32,          &Bs[b2][w * 16][0]);
        }
        const int cb = it % 3;
        bf16x8 af[4], bfr[4];
        for (int i = 0; i < 4; ++i) af[i]  = *(const bf16x8*)&As[cb][wm + i * 16 + l16][quad * 8];
        for (int i = 0; i < 4; ++i) bfr[i] = *(const bf16x8*)&Bs[cb][wn + i * 16 + l16][quad * 8];
        for (int mi = 0; mi < 4; ++mi)
            for (int ni = 0; ni < 4; ++ni)
                acc[mi][ni] = __builtin_amdgcn_mfma_f32_16x16x32_bf16(af[mi], bfr[ni], acc[mi][ni], 0, 0, 0);
    }

    for (int ni = 0; ni < 4; ++ni) {
        int col = n0 + wn + ni * 16 + l16;
        float bv = bias[col];
        for (int mi = 0; mi < 4; ++mi) {
            for (int r = 0; r < 4; ++r) {
                int m = m0 + wm + mi * 16 + quad * 4 + r;
                out[m * 1024 + col] = acc[mi][ni][r] + bv;
            }
        }
    }
}

extern "C" void kernel_launch(void* const* d_in, const int* in_sizes, int n_in,
                              void* d_out, int out_size, void* d_ws, size_t ws_size,
                              hipStream_t stream) {
    const float* x      = (const float*)d_in[0];
    const float* w_qkv  = (const float*)d_in[1];
    const float* w_proj = (const float*)d_in[2];
    const float* b_proj = (const float*)d_in[3];
    float* out = (float*)d_out;

    char* ws = (char*)d_ws;
    short* xb     = (short*)(ws);
    short* wqkvb  = (short*)(ws + 16777216);
    short* wprojb = (short*)(ws + 23068672);
    short* qb     = (short*)(ws + 25165824);
    short* kb     = (short*)(ws + 41943040);
    short* vtb    = (short*)(ws + 58720256);
    short* aob    = (short*)(ws + 75497472);

    convert_all<<<12288, 256, 0, stream>>>(x, w_qkv, w_proj, xb, wqkvb, wprojb);
    gemm_qkv<<<dim3(24, 32), 512, 0, stream>>>(xb, wqkvb, qb, kb, vtb);
    attn_kernel<<<dim3(8, 128), 256, 0, stream>>>(qb, kb, vtb, aob);
    gemm_proj<<<dim3(8, 32), 512, 0, stream>>>(aob, wprojb, b_proj, out);
}

// Round 12
// 267.510 us; speedup vs baseline: 1.0148x; 1.0148x over previous
//
#include <hip/hip_runtime.h>

// B=8, N=1024, C=1024, H=16, HD=64
// R12 = R11 with the syntax fix (unbalanced paren in sc8).
//      GEMMs: 128x128 / 4-wave / 3-stage vmcnt(4) + XOR chunk swizzle
//      (row r's 16B chunk c stored at c ^ ((r>>1)&3)); staging uses a
//      per-lane global source permutation (legal under the DMA constraint).
//      Falsification: SQ_LDS_BANK_CONFLICT must collapse 6.29M -> <1M.
//      Attention (R9 dbuf register-P) and convert unchanged.

typedef __attribute__((ext_vector_type(8))) short bf16x8;
typedef __attribute__((ext_vector_type(4))) short bf16x4;
typedef __attribute__((ext_vector_type(4))) float f32x4;

__device__ __forceinline__ short f2bf(float f) {
    union { float f; unsigned u; } x;
    x.f = f;
    unsigned r = x.u + 0x7fffu + ((x.u >> 16) & 1u);  // RNE
    return (short)(r >> 16);
}

__device__ __forceinline__ void load_lds16(const void* g, void* l) {
    __builtin_amdgcn_global_load_lds((const __attribute__((address_space(1))) unsigned*)g,
                                     (__attribute__((address_space(3))) unsigned*)l,
                                     16, 0, 0);
}

// ---------------- merged fp32 -> bf16 convert ----------------
__global__ __launch_bounds__(256) void convert_all(const float* __restrict__ x,
                                                   const float* __restrict__ wqkv,
                                                   const float* __restrict__ wproj,
                                                   short* __restrict__ xb,
                                                   short* __restrict__ wqkvb,
                                                   short* __restrict__ wprojb) {
    int i = blockIdx.x * 256 + threadIdx.x;
    const float* src;
    short* dst;
    int j;
    if (i < 2097152)      { src = x;     dst = xb;     j = i; }
    else if (i < 2883584) { src = wqkv;  dst = wqkvb;  j = i - 2097152; }
    else                  { src = wproj; dst = wprojb; j = i - 2883584; }
    float4 v = *(const float4*)(src + j * 4);
    unsigned lo = (unsigned short)f2bf(v.x) | ((unsigned)(unsigned short)f2bf(v.y) << 16);
    unsigned hi = (unsigned short)f2bf(v.z) | ((unsigned)(unsigned short)f2bf(v.w) << 16);
    uint2 p; p.x = lo; p.y = hi;
    *(uint2*)(dst + j * 4) = p;
}

// ---------------- QKV GEMM: 3-stage vmcnt(4) + XOR chunk swizzle ----------------
// M=8192, N=3072, K=1024. 128x128 tile, 4 waves (2x2 of 64x64).
__global__ __launch_bounds__(256) void gemm_qkv(const short* __restrict__ A,
                                                const short* __restrict__ Bt,
                                                short* __restrict__ q,
                                                short* __restrict__ k,
                                                short* __restrict__ vt) {
    __shared__ alignas(16) short As[3][128][32];
    __shared__ alignas(16) short Bs[3][128][32];
    const int K = 1024;
    const int m0 = blockIdx.y * 128;
    const int n0 = blockIdx.x * 128;
    const int t = threadIdx.x;
    const int w = t >> 6, lane = t & 63, quad = lane >> 4, l16 = lane & 15;
    const int wm = (w >> 1) * 64, wn = (w & 1) * 64;
    const int srow = lane >> 2;                                    // 0..15
    const int sc8 = (((lane & 3) ^ ((lane >> 3) & 3))) * 8;        // swizzled global chunk
    const int cq  = (quad ^ ((l16 >> 1) & 3)) * 8;                 // swizzled read col

    const short* Abase = &A[(m0 + w * 32 + srow) * K + sc8];
    const short* Bbase = &Bt[(n0 + w * 32 + srow) * K + sc8];

    f32x4 acc[4][4];
    for (int mi = 0; mi < 4; ++mi)
        for (int ni = 0; ni < 4; ++ni)
            acc[mi][ni] = (f32x4){0.f, 0.f, 0.f, 0.f};

    #pragma unroll
    for (int p = 0; p < 2; ++p) {
        load_lds16(Abase + p * 32,          &As[p][w * 32][0]);
        load_lds16(Abase + 16 * K + p * 32, &As[p][w * 32 + 16][0]);
        load_lds16(Bbase + p * 32,          &Bs[p][w * 32][0]);
        load_lds16(Bbase + 16 * K + p * 32, &Bs[p][w * 32 + 16][0]);
    }

    #pragma unroll
    for (int it = 0; it < 32; ++it) {
        if (it == 31) asm volatile("s_waitcnt vmcnt(0) lgkmcnt(0)" ::: "memory");
        else          asm volatile("s_waitcnt vmcnt(4) lgkmcnt(0)" ::: "memory");
        asm volatile("s_barrier" ::: "memory");
        if (it < 30) {
            const int b2 = (it + 2) % 3;
            load_lds16(Abase + (it + 2) * 32,          &As[b2][w * 32][0]);
            load_lds16(Abase + 16 * K + (it + 2) * 32, &As[b2][w * 32 + 16][0]);
            load_lds16(Bbase + (it + 2) * 32,          &Bs[b2][w * 32][0]);
            load_lds16(Bbase + 16 * K + (it + 2) * 32, &Bs[b2][w * 32 + 16][0]);
        }
        const int cb = it % 3;
        bf16x8 af[4], bfr[4];
        for (int i = 0; i < 4; ++i) af[i]  = *(const bf16x8*)&As[cb][wm + i * 16 + l16][cq];
        for (int i = 0; i < 4; ++i) bfr[i] = *(const bf16x8*)&Bs[cb][wn + i * 16 + l16][cq];
        for (int mi = 0; mi < 4; ++mi)
            for (int ni = 0; ni < 4; ++ni)
                acc[mi][ni] = __builtin_amdgcn_mfma_f32_16x16x32_bf16(af[mi], bfr[ni], acc[mi][ni], 0, 0, 0);
    }

    const float QS = 0.125f * 1.44269504088896f;
    for (int ni = 0; ni < 4; ++ni) {
        int col = n0 + wn + ni * 16 + l16;
        int sect = col >> 10;
        int c = col & 1023;
        int h = c >> 6, d = c & 63;
        for (int mi = 0; mi < 4; ++mi) {
            for (int r = 0; r < 4; ++r) {
                int m = m0 + wm + mi * 16 + quad * 4 + r;
                int b = m >> 10, i = m & 1023;
                float v = acc[mi][ni][r];
                if (sect == 0)      q[((b * 16 + h) * 1024 + i) * 64 + d] = f2bf(v * QS);
                else if (sect == 1) k[((b * 16 + h) * 1024 + i) * 64 + d] = f2bf(v);
                else                vt[((b * 16 + h) * 64 + d) * 1024 + i] = f2bf(v);
            }
        }
    }
}

// ---------------- Flash attention: dbuf K/V, 1 barrier/jt, register P (R9) ----------------
__global__ __launch_bounds__(256) void attn_kernel(const short* __restrict__ q,
                                                   const short* __restrict__ k,
                                                   const short* __restrict__ vt,
                                                   short* __restrict__ ao) {
    __shared__ alignas(16) short Ks[2][64][72];
    __shared__ alignas(16) short Vs[2][64][72];

    const int bh = blockIdx.y, qt = blockIdx.x;
    const int t = threadIdx.x, w = t >> 6, lane = t & 63, quad = lane >> 4, l16 = lane & 15;
    const short* qg = q  + (bh * 1024 + qt * 128) * 64;
    const short* kg = k  + bh * 65536;
    const short* vg = vt + bh * 65536;

    bf16x8 qf[2][2];
    for (int mi = 0; mi < 2; ++mi) {
        const short* qr = qg + (w * 32 + mi * 16 + l16) * 64;
        qf[mi][0] = *(const bf16x8*)(qr + quad * 8);
        qf[mi][1] = *(const bf16x8*)(qr + 32 + quad * 8);
    }

    const int r0 = t >> 3,          c80 = (t & 7) * 8;
    const int r1 = (t + 256) >> 3,  c81 = c80;

    float rs[2] = {0.f, 0.f};
    f32x4 oaccT[2][4];
    for (int mi = 0; mi < 2; ++mi)
        for (int dt = 0; dt < 4; ++dt) oaccT[mi][dt] = (f32x4){0.f, 0.f, 0.f, 0.f};

    {
        float4 a = *(const float4*)&kg[r0 * 64 + c80];
        float4 b = *(const float4*)&kg[r1 * 64 + c81];
        float4 c = *(const float4*)&vg[r0 * 1024 + c80];
        float4 d = *(const float4*)&vg[r1 * 1024 + c81];
        *(float4*)&Ks[0][r0][c80] = a;  *(float4*)&Ks[0][r1][c81] = b;
        *(float4*)&Vs[0][r0][c80] = c;  *(float4*)&Vs[0][r1][c81] = d;
    }

    for (int jt = 0; jt < 16; ++jt) {
        const int cur = jt & 1;
        asm volatile("s_waitcnt lgkmcnt(0)" ::: "memory");
        asm volatile("s_barrier" ::: "memory");

        float4 kr0, kr1, vr0, vr1;
        if (jt < 15) {
            int jn = jt + 1;
            kr0 = *(const float4*)&kg[(jn * 64 + r0) * 64 + c80];
            kr1 = *(const float4*)&kg[(jn * 64 + r1) * 64 + c81];
            vr0 = *(const float4*)&vg[r0 * 1024 + jn * 64 + c80];
            vr1 = *(const float4*)&vg[r1 * 1024 + jn * 64 + c81];
        }

        for (int js = 0; js < 4; ++js) {
            bf16x8 kf0 = *(const bf16x8*)&Ks[cur][js * 16 + l16][quad * 8];
            bf16x8 kf1 = *(const bf16x8*)&Ks[cur][js * 16 + l16][32 + quad * 8];
            bf16x4 vtf[4];
            for (int dt = 0; dt < 4; ++dt)
                vtf[dt] = *(const bf16x4*)&Vs[cur][dt * 16 + l16][js * 16 + quad * 4];
            for (int mi = 0; mi < 2; ++mi) {
                f32x4 s = (f32x4){0.f, 0.f, 0.f, 0.f};
                s = __builtin_amdgcn_mfma_f32_16x16x32_bf16(kf0, qf[mi][0], s, 0, 0, 0);
                s = __builtin_amdgcn_mfma_f32_16x16x32_bf16(kf1, qf[mi][1], s, 0, 0, 0);
                bf16x4 pfrag;
                for (int r = 0; r < 4; ++r) {
                    float p = __builtin_amdgcn_exp2f(s[r]);
                    rs[mi] += p;
                    pfrag[r] = f2bf(p);
                }
                for (int dt = 0; dt < 4; ++dt)
                    oaccT[mi][dt] = __builtin_amdgcn_mfma_f32_16x16x16bf16_1k(
                        vtf[dt], pfrag, oaccT[mi][dt], 0, 0, 0);
            }
        }

        if (jt < 15) {
            const int nxt = cur ^ 1;
            *(float4*)&Ks[nxt][r0][c80] = kr0;  *(float4*)&Ks[nxt][r1][c81] = kr1;
            *(float4*)&Vs[nxt][r0][c80] = vr0;  *(float4*)&Vs[nxt][r1][c81] = vr1;
        }
    }

    for (int mi = 0; mi < 2; ++mi) {
        rs[mi] += __shfl_xor(rs[mi], 16, 64);
        rs[mi] += __shfl_xor(rs[mi], 32, 64);
    }

    const int b = bh >> 4, h = bh & 15;
    for (int mi = 0; mi < 2; ++mi) {
        float inv = 1.0f / rs[mi];
        int i = qt * 128 + w * 32 + mi * 16 + l16;
        short* aor = ao + (b * 1024 + i) * 1024 + h * 64;
        for (int dt = 0; dt < 4; ++dt) {
            bf16x4 o4;
            for (int r = 0; r < 4; ++r) o4[r] = f2bf(oaccT[mi][dt][r] * inv);
            *(bf16x4*)(aor + dt * 16 + quad * 4) = o4;
        }
    }
}

// ---------------- Out-proj GEMM: 3-stage vmcnt(4) + XOR chunk swizzle ----------------
__global__ __launch_bounds__(256) void gemm_proj(const short* __restrict__ A,
                                                 const short* __restrict__ Bt,
                                                 const float* __restrict__ bias,
                                                 float* __restrict__ out) {
    __shared__ alignas(16) short As[3][128][32];
    __shared__ alignas(16) short Bs[3][128][32];
    const int K = 1024;
    const int m0 = blockIdx.y * 128;
    const int n0 = blockIdx.x * 128;
    const int t = threadIdx.x;
    const int w = t >> 6, lane = t & 63, quad = lane >> 4, l16 = lane & 15;
    const int wm = (w >> 1) * 64, wn = (w & 1) * 64;
    const int srow = lane >> 2;
    const int sc8 = (((lane & 3) ^ ((lane >> 3) & 3))) * 8;
    const int cq  = (quad ^ ((l16 >> 1) & 3)) * 8;

    const short* Abase = &A[(m0 + w * 32 + srow) * K + sc8];
    const short* Bbase = &Bt[(n0 + w * 32 + srow) * K + sc8];

    f32x4 acc[4][4];
    for (int mi = 0; mi < 4; ++mi)
        for (int ni = 0; ni < 4; ++ni)
            acc[mi][ni] = (f32x4){0.f, 0.f, 0.f, 0.f};

    #pragma unroll
    for (int p = 0; p < 2; ++p) {
        load_lds16(Abase + p * 32,          &As[p][w * 32][0]);
        load_lds16(Abase + 16 * K + p * 32, &As[p][w * 32 + 16][0]);
        load_lds16(Bbase + p * 32,          &Bs[p][w * 32][0]);
        load_lds16(Bbase + 16 * K + p * 32, &Bs[p][w * 32 + 16][0]);
    }

    #pragma unroll
    for (int it = 0; it < 32; ++it) {
        if (it == 31) asm volatile("s_waitcnt vmcnt(0) lgkmcnt(0)" ::: "memory");
        else          asm volatile("s_waitcnt vmcnt(4) lgkmcnt(0)" ::: "memory");
        asm volatile("s_barrier" ::: "memory");
        if (it < 30) {
            const int b2 = (it + 2) % 3;
            load_lds16(Abase + (it + 2) * 32,          &As[b2][w * 32][0]);
            load_lds16(Abase + 16 * K + (it + 2) * 32, &As[b2][w * 32 + 16][0]);
            load_lds16(Bbase + (it + 2) * 32,          &Bs[b2][w * 32][0]);
            load_lds16(Bbase + 16 * K + (it + 2) * 32, &Bs[b2][w * 32 + 16][0]);
        }
        const int cb = it % 3;
        bf16x8 af[4], bfr[4];
        for (int i = 0; i < 4; ++i) af[i]  = *(const bf16x8*)&As[cb][wm + i * 16 + l16][cq];
        for (int i = 0; i < 4; ++i) bfr[i] = *(const bf16x8*)&Bs[cb][wn + i * 16 + l16][cq];
        for (int mi = 0; mi < 4; ++mi)
            for (int ni = 0; ni < 4; ++ni)
                acc[mi][ni] = __builtin_amdgcn_mfma_f32_16x16x32_bf16(af[mi], bfr[ni], acc[mi][ni], 0, 0, 0);
    }

    for (int ni = 0; ni < 4; ++ni) {
        int col = n0 + wn + ni * 16 + l16;
        float bv = bias[col];
        for (int mi = 0; mi < 4; ++mi) {
            for (int r = 0; r < 4; ++r) {
                int m = m0 + wm + mi * 16 + quad * 4 + r;
                out[m * 1024 + col] = acc[mi][ni][r] + bv;
            }
        }
    }
}

extern "C" void kernel_launch(void* const* d_in, const int* in_sizes, int n_in,
                              void* d_out, int out_size, void* d_ws, size_t ws_size,
                              hipStream_t stream) {
    const float* x      = (const float*)d_in[0];
    const float* w_qkv  = (const float*)d_in[1];
    const float* w_proj = (const float*)d_in[2];
    const float* b_proj = (const float*)d_in[3];
    float* out = (float*)d_out;

    char* ws = (char*)d_ws;
    short* xb     = (short*)(ws);
    short* wqkvb  = (short*)(ws + 16777216);
    short* wprojb = (short*)(ws + 23068672);
    short* qb     = (short*)(ws + 25165824);
    short* kb     = (short*)(ws + 41943040);
    short* vtb    = (short*)(ws + 58720256);
    short* aob    = (short*)(ws + 75497472);

    convert_all<<<12288, 256, 0, stream>>>(x, w_qkv, w_proj, xb, wqkvb, wprojb);
    gemm_qkv<<<dim3(24, 64), 256, 0, stream>>>(xb, wqkvb, qb, kb, vtb);
    attn_kernel<<<dim3(8, 128), 256, 0, stream>>>(qb, kb, vtb, aob);
    gemm_proj<<<dim3(8, 64), 256, 0, stream>>>(aob, wprojb, b_proj, out);
}

// Round 13
// 265.509 us; speedup vs baseline: 1.0225x; 1.0075x over previous
//
#include <hip/hip_runtime.h>

// B=8, N=1024, C=1024, H=16, HD=64
// R13: GEMMs: __launch_bounds__(256,4) to force <=128 unified regs/wave
//      (64 AGPR acc + <=64 VGPR) -> 16 waves/CU = 4 blocks (was 2: the
//      132-reg allocation pinned us in the 2-waves/SIMD bin all session).
//      2-stage LDS (32KB, allows 5 blocks), dist-1 prefetch issued after the
//      barrier, conflict-free XOR swizzle retained (R12: conflicts = 0).
//      Attention (R9) and convert unchanged.

typedef __attribute__((ext_vector_type(8))) short bf16x8;
typedef __attribute__((ext_vector_type(4))) short bf16x4;
typedef __attribute__((ext_vector_type(4))) float f32x4;

__device__ __forceinline__ short f2bf(float f) {
    union { float f; unsigned u; } x;
    x.f = f;
    unsigned r = x.u + 0x7fffu + ((x.u >> 16) & 1u);  // RNE
    return (short)(r >> 16);
}

__device__ __forceinline__ void load_lds16(const void* g, void* l) {
    __builtin_amdgcn_global_load_lds((const __attribute__((address_space(1))) unsigned*)g,
                                     (__attribute__((address_space(3))) unsigned*)l,
                                     16, 0, 0);
}

// ---------------- merged fp32 -> bf16 convert ----------------
__global__ __launch_bounds__(256) void convert_all(const float* __restrict__ x,
                                                   const float* __restrict__ wqkv,
                                                   const float* __restrict__ wproj,
                                                   short* __restrict__ xb,
                                                   short* __restrict__ wqkvb,
                                                   short* __restrict__ wprojb) {
    int i = blockIdx.x * 256 + threadIdx.x;
    const float* src;
    short* dst;
    int j;
    if (i < 2097152)      { src = x;     dst = xb;     j = i; }
    else if (i < 2883584) { src = wqkv;  dst = wqkvb;  j = i - 2097152; }
    else                  { src = wproj; dst = wprojb; j = i - 2883584; }
    float4 v = *(const float4*)(src + j * 4);
    unsigned lo = (unsigned short)f2bf(v.x) | ((unsigned)(unsigned short)f2bf(v.y) << 16);
    unsigned hi = (unsigned short)f2bf(v.z) | ((unsigned)(unsigned short)f2bf(v.w) << 16);
    uint2 p; p.x = lo; p.y = hi;
    *(uint2*)(dst + j * 4) = p;
}

// ---------------- QKV GEMM: 2-stage dbuf, dist-1, 4 blocks/CU target ----------------
// M=8192, N=3072, K=1024. 128x128 tile, 4 waves (2x2 of 64x64).
__global__ __launch_bounds__(256, 4) void gemm_qkv(const short* __restrict__ A,
                                                   const short* __restrict__ Bt,
                                                   short* __restrict__ q,
                                                   short* __restrict__ k,
                                                   short* __restrict__ vt) {
    __shared__ alignas(16) short As[2][128][32];   // 2-stage: 32 KB total
    __shared__ alignas(16) short Bs[2][128][32];
    const int K = 1024;
    const int m0 = blockIdx.y * 128;
    const int n0 = blockIdx.x * 128;
    const int t = threadIdx.x;
    const int w = t >> 6, lane = t & 63, quad = lane >> 4, l16 = lane & 15;
    const int wm = (w >> 1) * 64, wn = (w & 1) * 64;
    const int srow = lane >> 2;                                    // 0..15
    const int sc8 = (((lane & 3) ^ ((lane >> 3) & 3))) * 8;        // swizzled global chunk
    const int cq  = (quad ^ ((l16 >> 1) & 3)) * 8;                 // swizzled read col

    const short* Abase = &A[(m0 + w * 32 + srow) * K + sc8];
    const short* Bbase = &Bt[(n0 + w * 32 + srow) * K + sc8];

    f32x4 acc[4][4];
    for (int mi = 0; mi < 4; ++mi)
        for (int ni = 0; ni < 4; ++ni)
            acc[mi][ni] = (f32x4){0.f, 0.f, 0.f, 0.f};

    // prologue: stage tile 0 into buffer 0
    load_lds16(Abase,          &As[0][w * 32][0]);
    load_lds16(Abase + 16 * K, &As[0][w * 32 + 16][0]);
    load_lds16(Bbase,          &Bs[0][w * 32][0]);
    load_lds16(Bbase + 16 * K, &Bs[0][w * 32 + 16][0]);

    #pragma unroll
    for (int it = 0; it < 32; ++it) {
        const int cur = it & 1;
        // drain own-tile loads; all waves' prior ds_reads retired (lgkm)
        asm volatile("s_waitcnt vmcnt(0) lgkmcnt(0)" ::: "memory");
        asm volatile("s_barrier" ::: "memory");
        if (it < 31) {
            // issue next-tile loads now: in flight during the whole compute phase
            const int nb = cur ^ 1;
            load_lds16(Abase + (it + 1) * 32,          &As[nb][w * 32][0]);
            load_lds16(Abase + 16 * K + (it + 1) * 32, &As[nb][w * 32 + 16][0]);
            load_lds16(Bbase + (it + 1) * 32,          &Bs[nb][w * 32][0]);
            load_lds16(Bbase + 16 * K + (it + 1) * 32, &Bs[nb][w * 32 + 16][0]);
        }
        bf16x8 af[4], bfr[4];
        for (int i = 0; i < 4; ++i) af[i]  = *(const bf16x8*)&As[cur][wm + i * 16 + l16][cq];
        for (int i = 0; i < 4; ++i) bfr[i] = *(const bf16x8*)&Bs[cur][wn + i * 16 + l16][cq];
        for (int mi = 0; mi < 4; ++mi)
            for (int ni = 0; ni < 4; ++ni)
                acc[mi][ni] = __builtin_amdgcn_mfma_f32_16x16x32_bf16(af[mi], bfr[ni], acc[mi][ni], 0, 0, 0);
    }

    const float QS = 0.125f * 1.44269504088896f;
    for (int ni = 0; ni < 4; ++ni) {
        int col = n0 + wn + ni * 16 + l16;
        int sect = col >> 10;
        int c = col & 1023;
        int h = c >> 6, d = c & 63;
        for (int mi = 0; mi < 4; ++mi) {
            for (int r = 0; r < 4; ++r) {
                int m = m0 + wm + mi * 16 + quad * 4 + r;
                int b = m >> 10, i = m & 1023;
                float v = acc[mi][ni][r];
                if (sect == 0)      q[((b * 16 + h) * 1024 + i) * 64 + d] = f2bf(v * QS);
                else if (sect == 1) k[((b * 16 + h) * 1024 + i) * 64 + d] = f2bf(v);
                else                vt[((b * 16 + h) * 64 + d) * 1024 + i] = f2bf(v);
            }
        }
    }
}

// ---------------- Flash attention: dbuf K/V, 1 barrier/jt, register P (R9) ----------------
__global__ __launch_bounds__(256) void attn_kernel(const short* __restrict__ q,
                                                   const short* __restrict__ k,
                                                   const short* __restrict__ vt,
                                                   short* __restrict__ ao) {
    __shared__ alignas(16) short Ks[2][64][72];
    __shared__ alignas(16) short Vs[2][64][72];

    const int bh = blockIdx.y, qt = blockIdx.x;
    const int t = threadIdx.x, w = t >> 6, lane = t & 63, quad = lane >> 4, l16 = lane & 15;
    const short* qg = q  + (bh * 1024 + qt * 128) * 64;
    const short* kg = k  + bh * 65536;
    const short* vg = vt + bh * 65536;

    bf16x8 qf[2][2];
    for (int mi = 0; mi < 2; ++mi) {
        const short* qr = qg + (w * 32 + mi * 16 + l16) * 64;
        qf[mi][0] = *(const bf16x8*)(qr + quad * 8);
        qf[mi][1] = *(const bf16x8*)(qr + 32 + quad * 8);
    }

    const int r0 = t >> 3,          c80 = (t & 7) * 8;
    const int r1 = (t + 256) >> 3,  c81 = c80;

    float rs[2] = {0.f, 0.f};
    f32x4 oaccT[2][4];
    for (int mi = 0; mi < 2; ++mi)
        for (int dt = 0; dt < 4; ++dt) oaccT[mi][dt] = (f32x4){0.f, 0.f, 0.f, 0.f};

    {
        float4 a = *(const float4*)&kg[r0 * 64 + c80];
        float4 b = *(const float4*)&kg[r1 * 64 + c81];
        float4 c = *(const float4*)&vg[r0 * 1024 + c80];
        float4 d = *(const float4*)&vg[r1 * 1024 + c81];
        *(float4*)&Ks[0][r0][c80] = a;  *(float4*)&Ks[0][r1][c81] = b;
        *(float4*)&Vs[0][r0][c80] = c;  *(float4*)&Vs[0][r1][c81] = d;
    }

    for (int jt = 0; jt < 16; ++jt) {
        const int cur = jt & 1;
        asm volatile("s_waitcnt lgkmcnt(0)" ::: "memory");
        asm volatile("s_barrier" ::: "memory");

        float4 kr0, kr1, vr0, vr1;
        if (jt < 15) {
            int jn = jt + 1;
            kr0 = *(const float4*)&kg[(jn * 64 + r0) * 64 + c80];
            kr1 = *(const float4*)&kg[(jn * 64 + r1) * 64 + c81];
            vr0 = *(const float4*)&vg[r0 * 1024 + jn * 64 + c80];
            vr1 = *(const float4*)&vg[r1 * 1024 + jn * 64 + c81];
        }

        for (int js = 0; js < 4; ++js) {
            bf16x8 kf0 = *(const bf16x8*)&Ks[cur][js * 16 + l16][quad * 8];
            bf16x8 kf1 = *(const bf16x8*)&Ks[cur][js * 16 + l16][32 + quad * 8];
            bf16x4 vtf[4];
            for (int dt = 0; dt < 4; ++dt)
                vtf[dt] = *(const bf16x4*)&Vs[cur][dt * 16 + l16][js * 16 + quad * 4];
            for (int mi = 0; mi < 2; ++mi) {
                f32x4 s = (f32x4){0.f, 0.f, 0.f, 0.f};
                s = __builtin_amdgcn_mfma_f32_16x16x32_bf16(kf0, qf[mi][0], s, 0, 0, 0);
                s = __builtin_amdgcn_mfma_f32_16x16x32_bf16(kf1, qf[mi][1], s, 0, 0, 0);
                bf16x4 pfrag;
                for (int r = 0; r < 4; ++r) {
                    float p = __builtin_amdgcn_exp2f(s[r]);
                    rs[mi] += p;
                    pfrag[r] = f2bf(p);
                }
                for (int dt = 0; dt < 4; ++dt)
                    oaccT[mi][dt] = __builtin_amdgcn_mfma_f32_16x16x16bf16_1k(
                        vtf[dt], pfrag, oaccT[mi][dt], 0, 0, 0);
            }
        }

        if (jt < 15) {
            const int nxt = cur ^ 1;
            *(float4*)&Ks[nxt][r0][c80] = kr0;  *(float4*)&Ks[nxt][r1][c81] = kr1;
            *(float4*)&Vs[nxt][r0][c80] = vr0;  *(float4*)&Vs[nxt][r1][c81] = vr1;
        }
    }

    for (int mi = 0; mi < 2; ++mi) {
        rs[mi] += __shfl_xor(rs[mi], 16, 64);
        rs[mi] += __shfl_xor(rs[mi], 32, 64);
    }

    const int b = bh >> 4, h = bh & 15;
    for (int mi = 0; mi < 2; ++mi) {
        float inv = 1.0f / rs[mi];
        int i = qt * 128 + w * 32 + mi * 16 + l16;
        short* aor = ao + (b * 1024 + i) * 1024 + h * 64;
        for (int dt = 0; dt < 4; ++dt) {
            bf16x4 o4;
            for (int r = 0; r < 4; ++r) o4[r] = f2bf(oaccT[mi][dt][r] * inv);
            *(bf16x4*)(aor + dt * 16 + quad * 4) = o4;
        }
    }
}

// ---------------- Out-proj GEMM: 2-stage dbuf, dist-1, 4 blocks/CU target ----------------
__global__ __launch_bounds__(256, 4) void gemm_proj(const short* __restrict__ A,
                                                    const short* __restrict__ Bt,
                                                    const float* __restrict__ bias,
                                                    float* __restrict__ out) {
    __shared__ alignas(16) short As[2][128][32];
    __shared__ alignas(16) short Bs[2][128][32];
    const int K = 1024;
    const int m0 = blockIdx.y * 128;
    const int n0 = blockIdx.x * 128;
    const int t = threadIdx.x;
    const int w = t >> 6, lane = t & 63, quad = lane >> 4, l16 = lane & 15;
    const int wm = (w >> 1) * 64, wn = (w & 1) * 64;
    const int srow = lane >> 2;
    const int sc8 = (((lane & 3) ^ ((lane >> 3) & 3))) * 8;
    const int cq  = (quad ^ ((l16 >> 1) & 3)) * 8;

    const short* Abase = &A[(m0 + w * 32 + srow) * K + sc8];
    const short* Bbase = &Bt[(n0 + w * 32 + srow) * K + sc8];

    f32x4 acc[4][4];
    for (int mi = 0; mi < 4; ++mi)
        for (int ni = 0; ni < 4; ++ni)
            acc[mi][ni] = (f32x4){0.f, 0.f, 0.f, 0.f};

    load_lds16(Abase,          &As[0][w * 32][0]);
    load_lds16(Abase + 16 * K, &As[0][w * 32 + 16][0]);
    load_lds16(Bbase,          &Bs[0][w * 32][0]);
    load_lds16(Bbase + 16 * K, &Bs[0][w * 32 + 16][0]);

    #pragma unroll
    for (int it = 0; it < 32; ++it) {
        const int cur = it & 1;
        asm volatile("s_waitcnt vmcnt(0) lgkmcnt(0)" ::: "memory");
        asm volatile("s_barrier" ::: "memory");
        if (it < 31) {
            const int nb = cur ^ 1;
            load_lds16(Abase + (it + 1) * 32,          &As[nb][w * 32][0]);
            load_lds16(Abase + 16 * K + (it + 1) * 32, &As[nb][w * 32 + 16][0]);
            load_lds16(Bbase + (it + 1) * 32,          &Bs[nb][w * 32][0]);
            load_lds16(Bbase + 16 * K + (it + 1) * 32, &Bs[nb][w * 32 + 16][0]);
        }
        bf16x8 af[4], bfr[4];
        for (int i = 0; i < 4; ++i) af[i]  = *(const bf16x8*)&As[cur][wm + i * 16 + l16][cq];
        for (int i = 0; i < 4; ++i) bfr[i] = *(const bf16x8*)&Bs[cur][wn + i * 16 + l16][cq];
        for (int mi = 0; mi < 4; ++mi)
            for (int ni = 0; ni < 4; ++ni)
                acc[mi][ni] = __builtin_amdgcn_mfma_f32_16x16x32_bf16(af[mi], bfr[ni], acc[mi][ni], 0, 0, 0);
    }

    for (int ni = 0; ni < 4; ++ni) {
        int col = n0 + wn + ni * 16 + l16;
        float bv = bias[col];
        for (int mi = 0; mi < 4; ++mi) {
            for (int r = 0; r < 4; ++r) {
                int m = m0 + wm + mi * 16 + quad * 4 + r;
                out[m * 1024 + col] = acc[mi][ni][r] + bv;
            }
        }
    }
}

extern "C" void kernel_launch(void* const* d_in, const int* in_sizes, int n_in,
                              void* d_out, int out_size, void* d_ws, size_t ws_size,
                              hipStream_t stream) {
    const float* x      = (const float*)d_in[0];
    const float* w_qkv  = (const float*)d_in[1];
    const float* w_proj = (const float*)d_in[2];
    const float* b_proj = (const float*)d_in[3];
    float* out = (float*)d_out;

    char* ws = (char*)d_ws;
    short* xb     = (short*)(ws);
    short* wqkvb  = (short*)(ws + 16777216);
    short* wprojb = (short*)(ws + 23068672);
    short* qb     = (short*)(ws + 25165824);
    short* kb     = (short*)(ws + 41943040);
    short* vtb    = (short*)(ws + 58720256);
    short* aob    = (short*)(ws + 75497472);

    convert_all<<<12288, 256, 0, stream>>>(x, w_qkv, w_proj, xb, wqkvb, wprojb);
    gemm_qkv<<<dim3(24, 64), 256, 0, stream>>>(xb, wqkvb, qb, kb, vtb);
    attn_kernel<<<dim3(8, 128), 256, 0, stream>>>(qb, kb, vtb, aob);
    gemm_proj<<<dim3(8, 64), 256, 0, stream>>>(aob, wprojb, b_proj, out);
}